// Round 1
// baseline (133.283 us; speedup 1.0000x reference)
//
#include <hip/hip_runtime.h>
#include <hip/hip_bf16.h>
#include <cstdint>

// DenseMRConv: out = concat([x, max_k(x[idx[n,k]] - x[n])]) @ W + b
// N=100000, K=32, d=64, d_out=64.
//
// R6 (on top of R5's max-first + prebuilt B-frags):
// (a) Deep gather pipeline: all 16 rows/lane loaded into r[16] before any
//     consume, pinned with sched_barrier(0). launch_bounds(256,5) caps VGPR
//     at ~102 (5 waves/SIMD = the 62% occupancy we already achieve) so the
//     compiler can't collapse the window back to 2-in-flight (R5 had VGPR=36
//     => ~6.7 loads in flight per CU, latency-bound).
// (b) xbf stores ORDER-PRESERVING bf16 keys (sign ? ~u : u|0x8000, unsigned-
//     monotone). The 32-deep max runs as packed v_pk_max_u16 (4 ops/row vs
//     ~12 unpack+f32-max), 4 dword shuffles instead of 8 float shuffles.
//     One inverse transform at the end; bf16 values bit-identical to R5.
// (c) Non-temporal ei loads + out stores (+ x loads in convert): single-touch
//     streams no longer evict the 12.8MB gather working set from per-XCD L2.

typedef __attribute__((ext_vector_type(8))) short short8;
typedef __attribute__((ext_vector_type(4))) float f4;
typedef __attribute__((ext_vector_type(8))) unsigned short u16x8;
typedef __attribute__((ext_vector_type(4))) unsigned int u32x4;

#define TILE 16
#define ROWS 168   // padded h row stride in bf16 elems (336 B, 16B-aligned)

__device__ __forceinline__ unsigned short f2bf(float f) {
  unsigned int u = __builtin_bit_cast(unsigned int, f);
  u += 0x7fffu + ((u >> 16) & 1u);          // round-to-nearest-even
  return (unsigned short)(u >> 16);
}
__device__ __forceinline__ unsigned int pack2(float a, float b) {
  return (unsigned int)f2bf(a) | ((unsigned int)f2bf(b) << 16);
}
__device__ __forceinline__ float bflo(unsigned int u) {
  return __builtin_bit_cast(float, u << 16);
}
__device__ __forceinline__ float bfhi(unsigned int u) {
  return __builtin_bit_cast(float, u & 0xffff0000u);
}
// bf16 -> unsigned-monotone key, per 16-bit half: sign ? ~u : u|0x8000
__device__ __forceinline__ unsigned int key2(unsigned int u) {
  unsigned int s = u & 0x80008000u;
  unsigned int m = (s >> 15) * 0x7fffu;            // 0x7fff where sign set
  return u ^ (0x80008000u | m);                    // ^0xffff (neg) / ^0x8000 (pos)
}
// inverse: key -> raw bf16 bits
__device__ __forceinline__ unsigned int unkey2(unsigned int k) {
  unsigned int s = k & 0x80008000u;
  unsigned int m = ((s >> 15) ^ 0x00010001u) * 0x7fffu; // 0x7fff where key-sign clear
  return k ^ (0x80008000u | m);
}
__device__ __forceinline__ u16x8 pmax8(u16x8 a, u16x8 b) {
  return __builtin_elementwise_max(a, b);          // 4x v_pk_max_u16
}

// ---- pass 1: x -> keyed bf16 copy (blocks [0,nxb)), W -> MFMA B-frags (block nxb)
__global__ __launch_bounds__(256)
void convert_kernel(const float* __restrict__ x, unsigned int* __restrict__ xbf,
                    const float* __restrict__ W, unsigned short* __restrict__ wf,
                    int n8, int nxb) {
  if ((int)blockIdx.x < nxb) {
    int i = blockIdx.x * 256 + threadIdx.x;
    if (i >= n8) return;
    const f4* p = (const f4*)x + (size_t)i * 2;
    f4 a = __builtin_nontemporal_load(p);
    f4 b = __builtin_nontemporal_load(p + 1);
    u32x4 w;
    w.x = key2(pack2(a.x, a.y)); w.y = key2(pack2(a.z, a.w));
    w.z = key2(pack2(b.x, b.y)); w.w = key2(pack2(b.z, b.w));
    __builtin_nontemporal_store(w, (u32x4*)xbf + i);
  } else {
    // 1024 short8 entries: entry (wv,ks,l) = B-frag for wave wv, k-slab ks.
    // Raw bf16 (feeds MFMA directly) -- NOT keyed.
    #pragma unroll
    for (int q = 0; q < 4; ++q) {
      int idx = threadIdx.x * 4 + q;
      int wv = idx >> 8, ks = (idx >> 6) & 3, l = idx & 63;
      int c = l & 15, g = l >> 4;
      short8 v;
      #pragma unroll
      for (int j = 0; j < 8; ++j)
        v[j] = (short)f2bf(W[(ks * 32 + g * 8 + j) * 64 + wv * 16 + c]);
      *(short8*)(wf + (size_t)idx * 8) = v;
    }
  }
}

// ---- pass 2: gather + packed-key max + MFMA GEMM. One block per 16-node tile.
__global__ __launch_bounds__(256, 5)
void mrconv3_kernel(const unsigned int* __restrict__ xbf,  // keyed bf16, 2/uint
                    const unsigned short* __restrict__ wf, // prebuilt B-frags
                    const int* __restrict__ ei,
                    const float* __restrict__ bias,
                    float* __restrict__ out,
                    int n_tiles)
{
  __shared__ __align__(16) unsigned short hs[TILE * ROWS];
  __shared__ __align__(16) int eis[TILE * 32];   // lane-major: [(t*2+h)*16 + q]
  __shared__ __align__(16) float otile[TILE * 64];

  const int tid  = threadIdx.x;
  const int wv   = tid >> 6;
  const int lane = tid & 63;
  const int c = lane & 15;         // MFMA col / m-row selector
  const int g = lane >> 4;         // MFMA quad group
  const int t2 = lane >> 4;        // which of this wave's 4 nodes
  const int h  = (lane >> 3) & 1;  // neighbor half (16 each)
  const int e  = lane & 7;         // 16B feature chunk

  const int node0 = blockIdx.x * TILE;
  const int t = wv * 4 + t2;       // node row within tile

  // ---- stage this tile's 512 indices, re-laid so each lane's 16 indices are
  // contiguous: eis[(t*2+h)*16 + q] = ei[t*32 + 2q + h]. Non-temporal read.
  {
    long long ev = __builtin_nontemporal_load(
        (const long long*)ei + (size_t)node0 * 16 + tid);
    const int ts = tid >> 4, qs = tid & 15;
    eis[ts * 32 + qs]      = (int)ev;          // slot 2q   (h=0)
    eis[ts * 32 + 16 + qs] = (int)(ev >> 32);  // slot 2q+1 (h=1)
  }
  __syncthreads();

  // ---- Phase A: 16 gather rows per lane, ALL issued before any consume.
  const char* __restrict__ xb = (const char*)xbf;
  const unsigned eoff = (unsigned)e * 16u;
  const u16x8 xrk = *(const u16x8*)(xb + ((unsigned)(node0 + t) * 128u + eoff));

  const int4* ip = (const int4*)&eis[(t * 2 + h) * 16];
  const int4 i0 = ip[0], i1 = ip[1], i2 = ip[2], i3 = ip[3];
  const int jj[16] = {i0.x, i0.y, i0.z, i0.w, i1.x, i1.y, i1.z, i1.w,
                      i2.x, i2.y, i2.z, i2.w, i3.x, i3.y, i3.z, i3.w};
  u16x8 r[16];
  #pragma unroll
  for (int q = 0; q < 16; ++q)
    r[q] = *(const u16x8*)(xb + ((unsigned)jj[q] * 128u + eoff));
  __builtin_amdgcn_sched_barrier(0);   // pin: loads stay before the reduce

  // packed-u16 max tree over keys (two chains to shorten dependencies)
  u16x8 ka = pmax8(r[0], r[1]);
  u16x8 kb = pmax8(r[2], r[3]);
  #pragma unroll
  for (int q = 4; q < 16; q += 4) {
    ka = pmax8(ka, pmax8(r[q],     r[q + 1]));
    kb = pmax8(kb, pmax8(r[q + 2], r[q + 3]));
  }
  u16x8 km = pmax8(ka, kb);

  // merge the h-pair (lane bit 3): 4 dword shuffles + 1 packed max
  u32x4 k4 = __builtin_bit_cast(u32x4, km);
  u32x4 s4;
  s4.x = (unsigned)__shfl_xor((int)k4.x, 8);
  s4.y = (unsigned)__shfl_xor((int)k4.y, 8);
  s4.z = (unsigned)__shfl_xor((int)k4.z, 8);
  s4.w = (unsigned)__shfl_xor((int)k4.w, 8);
  km = pmax8(km, __builtin_bit_cast(u16x8, s4));
  k4 = __builtin_bit_cast(u32x4, km);

  // un-key own row once (needed by both halves)
  const u32x4 xr4 = __builtin_bit_cast(u32x4, xrk);
  u32x4 xw;
  xw.x = unkey2(xr4.x); xw.y = unkey2(xr4.y);
  xw.z = unkey2(xr4.z); xw.w = unkey2(xr4.w);

  if (h == 0) {            // diff half: (max x_j) - x_i, in f32 then RNE pack
    const unsigned m0 = unkey2(k4.x), m1 = unkey2(k4.y);
    const unsigned m2 = unkey2(k4.z), m3 = unkey2(k4.w);
    u32x4 w;
    w.x = pack2(bflo(m0) - bflo(xw.x), bfhi(m0) - bfhi(xw.x));
    w.y = pack2(bflo(m1) - bflo(xw.y), bfhi(m1) - bfhi(xw.y));
    w.z = pack2(bflo(m2) - bflo(xw.z), bfhi(m2) - bfhi(xw.z));
    w.w = pack2(bflo(m3) - bflo(xw.w), bfhi(m3) - bfhi(xw.w));
    *(u32x4*)(hs + t * ROWS + 64 + e * 8) = w;
  } else {                 // x half: raw bf16 copy
    *(u32x4*)(hs + t * ROWS + e * 8) = xw;
  }

  // ---- B fragments: 4 coalesced 16B loads (issued here so their latency
  // hides under the barrier; wf is 16KB and L2-resident).
  short8 bfrag[4];
  #pragma unroll
  for (int ks = 0; ks < 4; ++ks)
    bfrag[ks] = *(const short8*)(wf + (size_t)((wv * 4 + ks) * 64 + lane) * 8);
  __syncthreads();

  // ---- Phase B: wave wv computes C[:, wv*16 : wv*16+16] via 4 MFMAs.
  f4 acc = {0.f, 0.f, 0.f, 0.f};
  #pragma unroll
  for (int ks = 0; ks < 4; ++ks) {
    // A layout: lane holds A[m=l&15][k=(l>>4)*8+j]
    short8 a = *(const short8*)(hs + c * ROWS + ks * 32 + g * 8);
    acc = __builtin_amdgcn_mfma_f32_16x16x32_bf16(a, bfrag[ks], acc, 0, 0, 0);
  }

  // ---- Epilogue: C layout col=lane&15, row=(lane>>4)*4+reg [m89-verified].
  const float bb = bias[wv * 16 + c];
  #pragma unroll
  for (int j = 0; j < 4; ++j)
    otile[(g * 4 + j) * 64 + wv * 16 + c] = acc[j] + bb;
  __syncthreads();
  __builtin_nontemporal_store(*(const f4*)&otile[tid * 4],
                              (f4*)(out + (size_t)node0 * 64) + tid);
}

// ---- fallback (ws too small): R2's proven fp32 kernel
#define FWPB 4
#define FROWS 160
__global__ __launch_bounds__(256, 4)
void mrconv_fp32_kernel(const float* __restrict__ x,
                        const int* __restrict__ ei,
                        const float* __restrict__ W,
                        const float* __restrict__ bias,
                        float* __restrict__ out,
                        int n_tiles)
{
  __shared__ __align__(16) unsigned short hsf[FWPB][TILE * FROWS];
  const int wave = threadIdx.x >> 6;
  const int lane = threadIdx.x & 63;
  const int c = lane & 15;
  const int g = lane >> 4;

  short8 bfrag[4][4];
  #pragma unroll
  for (int ks = 0; ks < 4; ++ks) {
    #pragma unroll
    for (int nt = 0; nt < 4; ++nt) {
      short8 v;
      #pragma unroll
      for (int j = 0; j < 8; ++j) {
        int k = ks * 32 + g * 8 + j;
        v[j] = (short)f2bf(W[k * 64 + nt * 16 + c]);
      }
      bfrag[ks][nt] = v;
    }
  }

  const int tile = blockIdx.x * FWPB + wave;
  if (tile >= n_tiles) return;
  const int node0 = tile * TILE;
  unsigned short* hrow = &hsf[wave][0];

  #pragma unroll 2
  for (int t = 0; t < TILE; ++t) {
    const int n = node0 + t;
    const f4 xi = *(const f4*)(x + (size_t)n * 64 + 4 * c);
    f4 m = { -3.4e38f, -3.4e38f, -3.4e38f, -3.4e38f };
    #pragma unroll
    for (int it = 0; it < 8; ++it) {
      const int j = ei[(size_t)n * 32 + it * 4 + g];
      const f4 xj = *(const f4*)(x + (size_t)j * 64 + 4 * c);
      m.x = fmaxf(m.x, xj.x - xi.x);
      m.y = fmaxf(m.y, xj.y - xi.y);
      m.z = fmaxf(m.z, xj.z - xi.z);
      m.w = fmaxf(m.w, xj.w - xi.w);
    }
    m.x = fmaxf(m.x, __shfl_xor(m.x, 16));
    m.y = fmaxf(m.y, __shfl_xor(m.y, 16));
    m.z = fmaxf(m.z, __shfl_xor(m.z, 16));
    m.w = fmaxf(m.w, __shfl_xor(m.w, 16));
    m.x = fmaxf(m.x, __shfl_xor(m.x, 32));
    m.y = fmaxf(m.y, __shfl_xor(m.y, 32));
    m.z = fmaxf(m.z, __shfl_xor(m.z, 32));
    m.w = fmaxf(m.w, __shfl_xor(m.w, 32));
    if (g == 0) {
      ushort4 p;
      p.x = f2bf(xi.x); p.y = f2bf(xi.y); p.z = f2bf(xi.z); p.w = f2bf(xi.w);
      *(ushort4*)(hrow + t * FROWS + 4 * c) = p;
    } else if (g == 1) {
      ushort4 p;
      p.x = f2bf(m.x); p.y = f2bf(m.y); p.z = f2bf(m.z); p.w = f2bf(m.w);
      *(ushort4*)(hrow + t * FROWS + 64 + 4 * c) = p;
    }
  }
  __asm__ volatile("s_waitcnt lgkmcnt(0)" ::: "memory");

  f4 acc[4] = {{0.f,0.f,0.f,0.f},{0.f,0.f,0.f,0.f},{0.f,0.f,0.f,0.f},{0.f,0.f,0.f,0.f}};
  #pragma unroll
  for (int ks = 0; ks < 4; ++ks) {
    short8 a = *(const short8*)(hrow + c * FROWS + ks * 32 + g * 8);
    #pragma unroll
    for (int nt = 0; nt < 4; ++nt)
      acc[nt] = __builtin_amdgcn_mfma_f32_16x16x32_bf16(a, bfrag[ks][nt], acc[nt], 0, 0, 0);
  }
  const int rbase = node0 + g * 4;
  #pragma unroll
  for (int nt = 0; nt < 4; ++nt) {
    const float bb = bias[nt * 16 + c];
    #pragma unroll
    for (int j = 0; j < 4; ++j)
      out[(size_t)(rbase + j) * 64 + nt * 16 + c] = acc[nt][j] + bb;
  }
}

extern "C" void kernel_launch(void* const* d_in, const int* in_sizes, int n_in,
                              void* d_out, int out_size, void* d_ws, size_t ws_size,
                              hipStream_t stream) {
  const float* x  = (const float*)d_in[0];
  const int*   ei = (const int*)d_in[1];     // int64 in reference -> int32 here
  const float* W  = (const float*)d_in[2];
  const float* b  = (const float*)d_in[3];
  float* out = (float*)d_out;

  const int N = in_sizes[0] / 64;            // 100000
  const int n_tiles = N / TILE;              // 6250

  const size_t xbf_bytes = (size_t)N * 64 * 2;   // 12.8 MB
  const size_t wf_bytes  = 1024 * 16;            // 16 KB of B-frags
  if (ws_size >= xbf_bytes + wf_bytes) {
    unsigned int*   xbf = (unsigned int*)d_ws;
    unsigned short* wf  = (unsigned short*)((char*)d_ws + xbf_bytes);
    const int n8  = N * 64 / 8;                  // 800000
    const int nxb = (n8 + 255) / 256;            // 3125
    hipLaunchKernelGGL(convert_kernel, dim3(nxb + 1), dim3(256), 0, stream,
                       x, xbf, W, wf, n8, nxb);
    hipLaunchKernelGGL(mrconv3_kernel, dim3(n_tiles), dim3(256), 0, stream,
                       xbf, wf, ei, b, out, n_tiles);
  } else {
    const int blocks = (n_tiles + FWPB - 1) / FWPB;
    hipLaunchKernelGGL(mrconv_fp32_kernel, dim3(blocks), dim3(256), 0, stream,
                       x, ei, W, b, out, n_tiles);
  }
}

// Round 2
// 132.607 us; speedup vs baseline: 1.0051x; 1.0051x over previous
//
#include <hip/hip_runtime.h>
#include <hip/hip_bf16.h>
#include <cstdint>

// DenseMRConv: out = concat([x, max_k(x[idx[n,k]] - x[n])]) @ W + b
// N=100000, K=32, d=64, d_out=64.
//
// R7: R6's intrinsic gather loads collapsed to a ~2-deep window (VGPR=40,
// dur unchanged despite 2.5x VALU cut => latency-bound on gathers).
// (a) Gathers now issued as asm volatile global_load_dwordx4 (saddr+voffset):
//     16 destination tuples are architecturally live until the explicit
//     s_waitcnt vmcnt(0) + sched_barrier(0), forcing a 16-deep MLP window
//     per lane. launch_bounds(256,4) budgets 128 VGPR for it.
// (b) xbf store in convert is no longer non-temporal: the gather working set
//     (12.8 MB) is exactly what we want resident in L2/L3. nt stays on the
//     single-touch ei/out streams.
// Kept from R6: max-first, packed-u16 order-preserving-key max (v_pk_max_u16),
// lane-major eis staging, prebuilt W B-frags.

typedef __attribute__((ext_vector_type(8))) short short8;
typedef __attribute__((ext_vector_type(4))) float f4;
typedef __attribute__((ext_vector_type(8))) unsigned short u16x8;
typedef __attribute__((ext_vector_type(4))) unsigned int u32x4;

#define TILE 16
#define ROWS 168   // padded h row stride in bf16 elems (336 B, 16B-aligned)

__device__ __forceinline__ unsigned short f2bf(float f) {
  unsigned int u = __builtin_bit_cast(unsigned int, f);
  u += 0x7fffu + ((u >> 16) & 1u);          // round-to-nearest-even
  return (unsigned short)(u >> 16);
}
__device__ __forceinline__ unsigned int pack2(float a, float b) {
  return (unsigned int)f2bf(a) | ((unsigned int)f2bf(b) << 16);
}
__device__ __forceinline__ float bflo(unsigned int u) {
  return __builtin_bit_cast(float, u << 16);
}
__device__ __forceinline__ float bfhi(unsigned int u) {
  return __builtin_bit_cast(float, u & 0xffff0000u);
}
// bf16 -> unsigned-monotone key, per 16-bit half: sign ? ~u : u|0x8000
__device__ __forceinline__ unsigned int key2(unsigned int u) {
  unsigned int s = u & 0x80008000u;
  unsigned int m = (s >> 15) * 0x7fffu;            // 0x7fff where sign set
  return u ^ (0x80008000u | m);                    // ^0xffff (neg) / ^0x8000 (pos)
}
// inverse: key -> raw bf16 bits
__device__ __forceinline__ unsigned int unkey2(unsigned int k) {
  unsigned int s = k & 0x80008000u;
  unsigned int m = ((s >> 15) ^ 0x00010001u) * 0x7fffu; // 0x7fff where key-sign clear
  return k ^ (0x80008000u | m);
}
__device__ __forceinline__ u16x8 pmax8(u16x8 a, u16x8 b) {
  return __builtin_elementwise_max(a, b);          // 4x v_pk_max_u16
}

// ---- pass 1: x -> keyed bf16 copy (blocks [0,nxb)), W -> MFMA B-frags (block nxb)
__global__ __launch_bounds__(256)
void convert_kernel(const float* __restrict__ x, unsigned int* __restrict__ xbf,
                    const float* __restrict__ W, unsigned short* __restrict__ wf,
                    int n8, int nxb) {
  if ((int)blockIdx.x < nxb) {
    int i = blockIdx.x * 256 + threadIdx.x;
    if (i >= n8) return;
    const f4* p = (const f4*)x + (size_t)i * 2;
    f4 a = __builtin_nontemporal_load(p);
    f4 b = __builtin_nontemporal_load(p + 1);
    u32x4 w;
    w.x = key2(pack2(a.x, a.y)); w.y = key2(pack2(a.z, a.w));
    w.z = key2(pack2(b.x, b.y)); w.w = key2(pack2(b.z, b.w));
    ((u32x4*)xbf)[i] = w;                    // regular store: keep L2/L3-resident
  } else {
    // 1024 short8 entries: entry (wv,ks,l) = B-frag for wave wv, k-slab ks.
    // Raw bf16 (feeds MFMA directly) -- NOT keyed.
    #pragma unroll
    for (int q = 0; q < 4; ++q) {
      int idx = threadIdx.x * 4 + q;
      int wv = idx >> 8, ks = (idx >> 6) & 3, l = idx & 63;
      int c = l & 15, g = l >> 4;
      short8 v;
      #pragma unroll
      for (int j = 0; j < 8; ++j)
        v[j] = (short)f2bf(W[(ks * 32 + g * 8 + j) * 64 + wv * 16 + c]);
      *(short8*)(wf + (size_t)idx * 8) = v;
    }
  }
}

// ---- pass 2: gather + packed-key max + MFMA GEMM. One block per 16-node tile.
__global__ __launch_bounds__(256, 4)
void mrconv3_kernel(const unsigned int* __restrict__ xbf,  // keyed bf16, 2/uint
                    const unsigned short* __restrict__ wf, // prebuilt B-frags
                    const int* __restrict__ ei,
                    const float* __restrict__ bias,
                    float* __restrict__ out,
                    int n_tiles)
{
  __shared__ __align__(16) unsigned short hs[TILE * ROWS];
  __shared__ __align__(16) int eis[TILE * 32];   // lane-major: [(t*2+h)*16 + q]
  __shared__ __align__(16) float otile[TILE * 64];

  const int tid  = threadIdx.x;
  const int wv   = tid >> 6;
  const int lane = tid & 63;
  const int c = lane & 15;         // MFMA col / m-row selector
  const int g = lane >> 4;         // MFMA quad group
  const int t2 = lane >> 4;        // which of this wave's 4 nodes
  const int h  = (lane >> 3) & 1;  // neighbor half (16 each)
  const int e  = lane & 7;         // 16B feature chunk

  const int node0 = blockIdx.x * TILE;
  const int t = wv * 4 + t2;       // node row within tile

  // ---- stage this tile's 512 indices, re-laid so each lane's 16 indices are
  // contiguous: eis[(t*2+h)*16 + q] = ei[t*32 + 2q + h]. Non-temporal read.
  {
    long long ev = __builtin_nontemporal_load(
        (const long long*)ei + (size_t)node0 * 16 + tid);
    const int ts = tid >> 4, qs = tid & 15;
    eis[ts * 32 + qs]      = (int)ev;          // slot 2q   (h=0)
    eis[ts * 32 + 16 + qs] = (int)(ev >> 32);  // slot 2q+1 (h=1)
  }
  __syncthreads();

  // ---- Phase A: 16 gather rows per lane, issued via inline asm so ALL 16
  // stay architecturally in flight until the single vmcnt(0) drain.
  const char* __restrict__ xb = (const char*)xbf;
  const unsigned eoff = (unsigned)e * 16u;
  const u16x8 xrk = *(const u16x8*)(xb + ((unsigned)(node0 + t) * 128u + eoff));

  const int4* ip = (const int4*)&eis[(t * 2 + h) * 16];
  const int4 i0 = ip[0], i1 = ip[1], i2 = ip[2], i3 = ip[3];
  const int jj[16] = {i0.x, i0.y, i0.z, i0.w, i1.x, i1.y, i1.z, i1.w,
                      i2.x, i2.y, i2.z, i2.w, i3.x, i3.y, i3.z, i3.w};
  u16x8 r[16];
  #pragma unroll
  for (int q = 0; q < 16; ++q) {
    const unsigned vo = ((unsigned)jj[q] << 7) + eoff;   // jj*128 + e*16
    asm volatile("global_load_dwordx4 %0, %1, %2"
                 : "=v"(r[q]) : "v"(vo), "s"(xbf));
  }
  asm volatile("s_waitcnt vmcnt(0)" ::: "memory");
  __builtin_amdgcn_sched_barrier(0);   // rule #18: no consume hoists above wait

  // packed-u16 max tree over keys (two chains to shorten dependencies)
  u16x8 ka = pmax8(r[0], r[1]);
  u16x8 kb = pmax8(r[2], r[3]);
  #pragma unroll
  for (int q = 4; q < 16; q += 4) {
    ka = pmax8(ka, pmax8(r[q],     r[q + 1]));
    kb = pmax8(kb, pmax8(r[q + 2], r[q + 3]));
  }
  u16x8 km = pmax8(ka, kb);

  // merge the h-pair (lane bit 3): 4 dword shuffles + 1 packed max
  u32x4 k4 = __builtin_bit_cast(u32x4, km);
  u32x4 s4;
  s4.x = (unsigned)__shfl_xor((int)k4.x, 8);
  s4.y = (unsigned)__shfl_xor((int)k4.y, 8);
  s4.z = (unsigned)__shfl_xor((int)k4.z, 8);
  s4.w = (unsigned)__shfl_xor((int)k4.w, 8);
  km = pmax8(km, __builtin_bit_cast(u16x8, s4));
  k4 = __builtin_bit_cast(u32x4, km);

  // un-key own row once (needed by both halves)
  const u32x4 xr4 = __builtin_bit_cast(u32x4, xrk);
  u32x4 xw;
  xw.x = unkey2(xr4.x); xw.y = unkey2(xr4.y);
  xw.z = unkey2(xr4.z); xw.w = unkey2(xr4.w);

  if (h == 0) {            // diff half: (max x_j) - x_i, in f32 then RNE pack
    const unsigned m0 = unkey2(k4.x), m1 = unkey2(k4.y);
    const unsigned m2 = unkey2(k4.z), m3 = unkey2(k4.w);
    u32x4 w;
    w.x = pack2(bflo(m0) - bflo(xw.x), bfhi(m0) - bfhi(xw.x));
    w.y = pack2(bflo(m1) - bflo(xw.y), bfhi(m1) - bfhi(xw.y));
    w.z = pack2(bflo(m2) - bflo(xw.z), bfhi(m2) - bfhi(xw.z));
    w.w = pack2(bflo(m3) - bflo(xw.w), bfhi(m3) - bfhi(xw.w));
    *(u32x4*)(hs + t * ROWS + 64 + e * 8) = w;
  } else {                 // x half: raw bf16 copy
    *(u32x4*)(hs + t * ROWS + e * 8) = xw;
  }

  // ---- B fragments: 4 coalesced 16B loads (wf is 16KB, L2-resident; latency
  // hides under the barrier).
  short8 bfrag[4];
  #pragma unroll
  for (int ks = 0; ks < 4; ++ks)
    bfrag[ks] = *(const short8*)(wf + (size_t)((wv * 4 + ks) * 64 + lane) * 8);
  __syncthreads();

  // ---- Phase B: wave wv computes C[:, wv*16 : wv*16+16] via 4 MFMAs.
  f4 acc = {0.f, 0.f, 0.f, 0.f};
  #pragma unroll
  for (int ks = 0; ks < 4; ++ks) {
    // A layout: lane holds A[m=l&15][k=(l>>4)*8+j]
    short8 a = *(const short8*)(hs + c * ROWS + ks * 32 + g * 8);
    acc = __builtin_amdgcn_mfma_f32_16x16x32_bf16(a, bfrag[ks], acc, 0, 0, 0);
  }

  // ---- Epilogue: C layout col=lane&15, row=(lane>>4)*4+reg [m89-verified].
  const float bb = bias[wv * 16 + c];
  #pragma unroll
  for (int j = 0; j < 4; ++j)
    otile[(g * 4 + j) * 64 + wv * 16 + c] = acc[j] + bb;
  __syncthreads();
  __builtin_nontemporal_store(*(const f4*)&otile[tid * 4],
                              (f4*)(out + (size_t)node0 * 64) + tid);
}

// ---- fallback (ws too small): R2's proven fp32 kernel
#define FWPB 4
#define FROWS 160
__global__ __launch_bounds__(256, 4)
void mrconv_fp32_kernel(const float* __restrict__ x,
                        const int* __restrict__ ei,
                        const float* __restrict__ W,
                        const float* __restrict__ bias,
                        float* __restrict__ out,
                        int n_tiles)
{
  __shared__ __align__(16) unsigned short hsf[FWPB][TILE * FROWS];
  const int wave = threadIdx.x >> 6;
  const int lane = threadIdx.x & 63;
  const int c = lane & 15;
  const int g = lane >> 4;

  short8 bfrag[4][4];
  #pragma unroll
  for (int ks = 0; ks < 4; ++ks) {
    #pragma unroll
    for (int nt = 0; nt < 4; ++nt) {
      short8 v;
      #pragma unroll
      for (int j = 0; j < 8; ++j) {
        int k = ks * 32 + g * 8 + j;
        v[j] = (short)f2bf(W[k * 64 + nt * 16 + c]);
      }
      bfrag[ks][nt] = v;
    }
  }

  const int tile = blockIdx.x * FWPB + wave;
  if (tile >= n_tiles) return;
  const int node0 = tile * TILE;
  unsigned short* hrow = &hsf[wave][0];

  #pragma unroll 2
  for (int t = 0; t < TILE; ++t) {
    const int n = node0 + t;
    const f4 xi = *(const f4*)(x + (size_t)n * 64 + 4 * c);
    f4 m = { -3.4e38f, -3.4e38f, -3.4e38f, -3.4e38f };
    #pragma unroll
    for (int it = 0; it < 8; ++it) {
      const int j = ei[(size_t)n * 32 + it * 4 + g];
      const f4 xj = *(const f4*)(x + (size_t)j * 64 + 4 * c);
      m.x = fmaxf(m.x, xj.x - xi.x);
      m.y = fmaxf(m.y, xj.y - xi.y);
      m.z = fmaxf(m.z, xj.z - xi.z);
      m.w = fmaxf(m.w, xj.w - xi.w);
    }
    m.x = fmaxf(m.x, __shfl_xor(m.x, 16));
    m.y = fmaxf(m.y, __shfl_xor(m.y, 16));
    m.z = fmaxf(m.z, __shfl_xor(m.z, 16));
    m.w = fmaxf(m.w, __shfl_xor(m.w, 16));
    m.x = fmaxf(m.x, __shfl_xor(m.x, 32));
    m.y = fmaxf(m.y, __shfl_xor(m.y, 32));
    m.z = fmaxf(m.z, __shfl_xor(m.z, 32));
    m.w = fmaxf(m.w, __shfl_xor(m.w, 32));
    if (g == 0) {
      ushort4 p;
      p.x = f2bf(xi.x); p.y = f2bf(xi.y); p.z = f2bf(xi.z); p.w = f2bf(xi.w);
      *(ushort4*)(hrow + t * FROWS + 4 * c) = p;
    } else if (g == 1) {
      ushort4 p;
      p.x = f2bf(m.x); p.y = f2bf(m.y); p.z = f2bf(m.z); p.w = f2bf(m.w);
      *(ushort4*)(hrow + t * FROWS + 64 + 4 * c) = p;
    }
  }
  __asm__ volatile("s_waitcnt lgkmcnt(0)" ::: "memory");

  f4 acc[4] = {{0.f,0.f,0.f,0.f},{0.f,0.f,0.f,0.f},{0.f,0.f,0.f,0.f},{0.f,0.f,0.f,0.f}};
  #pragma unroll
  for (int ks = 0; ks < 4; ++ks) {
    short8 a = *(const short8*)(hrow + c * FROWS + ks * 32 + g * 8);
    #pragma unroll
    for (int nt = 0; nt < 4; ++nt)
      acc[nt] = __builtin_amdgcn_mfma_f32_16x16x32_bf16(a, bfrag[ks][nt], acc[nt], 0, 0, 0);
  }
  const int rbase = node0 + g * 4;
  #pragma unroll
  for (int nt = 0; nt < 4; ++nt) {
    const float bb = bias[nt * 16 + c];
    #pragma unroll
    for (int j = 0; j < 4; ++j)
      out[(size_t)(rbase + j) * 64 + nt * 16 + c] = acc[nt][j] + bb;
  }
}

extern "C" void kernel_launch(void* const* d_in, const int* in_sizes, int n_in,
                              void* d_out, int out_size, void* d_ws, size_t ws_size,
                              hipStream_t stream) {
  const float* x  = (const float*)d_in[0];
  const int*   ei = (const int*)d_in[1];     // int64 in reference -> int32 here
  const float* W  = (const float*)d_in[2];
  const float* b  = (const float*)d_in[3];
  float* out = (float*)d_out;

  const int N = in_sizes[0] / 64;            // 100000
  const int n_tiles = N / TILE;              // 6250

  const size_t xbf_bytes = (size_t)N * 64 * 2;   // 12.8 MB
  const size_t wf_bytes  = 1024 * 16;            // 16 KB of B-frags
  if (ws_size >= xbf_bytes + wf_bytes) {
    unsigned int*   xbf = (unsigned int*)d_ws;
    unsigned short* wf  = (unsigned short*)((char*)d_ws + xbf_bytes);
    const int n8  = N * 64 / 8;                  // 800000
    const int nxb = (n8 + 255) / 256;            // 3125
    hipLaunchKernelGGL(convert_kernel, dim3(nxb + 1), dim3(256), 0, stream,
                       x, xbf, W, wf, n8, nxb);
    hipLaunchKernelGGL(mrconv3_kernel, dim3(n_tiles), dim3(256), 0, stream,
                       xbf, wf, ei, b, out, n_tiles);
  } else {
    const int blocks = (n_tiles + FWPB - 1) / FWPB;
    hipLaunchKernelGGL(mrconv_fp32_kernel, dim3(blocks), dim3(256), 0, stream,
                       x, ei, W, b, out, n_tiles);
  }
}